// Round 1
// baseline (4627.453 us; speedup 1.0000x reference)
//
#include <hip/hip_runtime.h>

// LSTM: L=2 layers, B=32, T=256, N=M=1024, gates 4M=4096
// d_in: x(B,T,N) h(L,B,M) c(L,B,M) Wih(L,4M,N) Whh(L,4M,M) bih(L,4M) bhh(L,4M), all fp32
// d_out: outs(B,T,M) ++ h_final(L,B,M) ++ c_final(L,B,M), fp32

typedef __bf16 bf16x8 __attribute__((ext_vector_type(8)));
typedef float  f32x4  __attribute__((ext_vector_type(4)));

__device__ __forceinline__ unsigned short f2bf(float f) {
    union { float f; unsigned u; } v; v.f = f;
    unsigned u = v.u;
    unsigned r = u + 0x7fffu + ((u >> 16) & 1u);   // RNE
    return (unsigned short)(r >> 16);
}
__device__ __forceinline__ float bf2f(unsigned short b) {
    union { unsigned u; float f; } v; v.u = ((unsigned)b) << 16;
    return v.f;
}
__device__ __forceinline__ float sigmoidf_fast(float x) {
    return 1.0f / (1.0f + __expf(-x));
}
// NaN-safe tanh: x->+inf gives 1-0, x->-inf gives 1-2 = -1
__device__ __forceinline__ float tanhf_fast(float x) {
    return 1.0f - 2.0f / (__expf(2.0f * x) + 1.0f);
}

__global__ void cvt_f32_to_bf16(const float* __restrict__ src,
                                unsigned short* __restrict__ dst, int n4) {
    int i = blockIdx.x * blockDim.x + threadIdx.x;
    int stride = gridDim.x * blockDim.x;
    for (; i < n4; i += stride) {
        float4 v = ((const float4*)src)[i];
        ushort4 o;
        o.x = f2bf(v.x); o.y = f2bf(v.y); o.z = f2bf(v.z); o.w = f2bf(v.w);
        ((ushort4*)dst)[i] = o;
    }
}

// C[r][j] = sum_k A[r][k]*W[j][k] + bih[j] + bhh[j]   (both operands K-contiguous, NT GEMM)
// A: R x 1024 bf16, W: 4096 x 1024 bf16, C: R x 4096 bf16. grid (R/64, 64), block 256.
__global__ __launch_bounds__(256) void gemm_proj(
    const unsigned short* __restrict__ A, const unsigned short* __restrict__ W,
    const float* __restrict__ bih, const float* __restrict__ bhh,
    unsigned short* __restrict__ C)
{
    __shared__ __align__(16) unsigned short Ash[64][40];  // +8 pad: 2-way-max banks
    __shared__ __align__(16) unsigned short Bsh[64][40];
    const int tid  = threadIdx.x;
    const int lane = tid & 63;
    const int w    = tid >> 6;
    const int wm   = w & 1, wn = w >> 1;
    const int row0 = blockIdx.x * 64;
    const int col0 = blockIdx.y * 64;
    const int srow = tid >> 2;           // 0..63
    const int sseg = (tid & 3) * 8;      // 0,8,16,24 (elems)
    const int lrow = lane & 15;
    const int lk   = (lane >> 4) * 8;    // k offset within 32-chunk

    f32x4 acc[2][2] = {};

    for (int k0 = 0; k0 < 1024; k0 += 32) {
        __syncthreads();
        *(uint4*)&Ash[srow][sseg] = *(const uint4*)&A[(size_t)(row0 + srow) * 1024 + k0 + sseg];
        *(uint4*)&Bsh[srow][sseg] = *(const uint4*)&W[(size_t)(col0 + srow) * 1024 + k0 + sseg];
        __syncthreads();
        bf16x8 af[2], bfrag[2];
        af[0]    = *(const bf16x8*)&Ash[wm * 32 + lrow     ][lk];
        af[1]    = *(const bf16x8*)&Ash[wm * 32 + 16 + lrow][lk];
        bfrag[0] = *(const bf16x8*)&Bsh[wn * 32 + lrow     ][lk];
        bfrag[1] = *(const bf16x8*)&Bsh[wn * 32 + 16 + lrow][lk];
        #pragma unroll
        for (int i = 0; i < 2; i++)
            #pragma unroll
            for (int j = 0; j < 2; j++)
                acc[i][j] = __builtin_amdgcn_mfma_f32_16x16x32_bf16(af[i], bfrag[j], acc[i][j], 0, 0, 0);
    }

    #pragma unroll
    for (int i = 0; i < 2; i++) {
        int r = row0 + wm * 32 + i * 16 + (lane >> 4) * 4;
        #pragma unroll
        for (int j = 0; j < 2; j++) {
            int cc = col0 + wn * 32 + j * 16 + (lane & 15);
            float bsum = bih[cc] + bhh[cc];
            #pragma unroll
            for (int rr = 0; rr < 4; rr++)
                C[(size_t)(r + rr) * 4096 + cc] = f2bf(acc[i][j][rr] + bsum);
        }
    }
}

// One LSTM cell step for one layer. grid 64 blocks x 256 thr (4 waves).
// Block owns m in [m0, m0+16). Wave w owns vc = mi*4+g for mi in [4w,4w+4), all 4 gates,
// so the i/f/g/o regroup is wave-local (2KB LDS exchange).
__global__ __launch_bounds__(256) void lstm_step(
    const unsigned short* __restrict__ Whh,    // 4096 x 1024 bf16
    const unsigned short* __restrict__ xproj,  // 8192 x 4096 bf16 (bias folded in)
    const unsigned short* __restrict__ h_in,   // 32 x 1024 bf16
    unsigned short* __restrict__ h_out,        // 32 x 1024 bf16
    float* __restrict__ hF,                    // 32 x 1024 f32 (final-state scratch)
    float* __restrict__ c_st,                  // 32 x 1024 f32
    unsigned short* __restrict__ seq_bf,       // (B,T,M) bf16 or null
    float* __restrict__ seq_f32,               // (B,T,M) f32 or null
    int t)
{
    __shared__ __align__(16) unsigned short hsh[32][520];  // 32 x 512 bf16, +8 pad
    __shared__ __align__(16) float gsh[4][32][20];
    const int tid  = threadIdx.x;
    const int lane = tid & 63;
    const int w    = tid >> 6;
    const int m0   = blockIdx.x * 16;

    const int n  = lane & 15;
    const int vc = w * 16 + n;
    const int mi = vc >> 2;
    const int g  = vc & 3;
    const size_t jrow = (size_t)(g * 1024 + m0 + mi);  // row of Whh / col of gates
    const int lk = (lane >> 4) * 8;

    f32x4 acc0 = {0.f, 0.f, 0.f, 0.f}, acc1 = {0.f, 0.f, 0.f, 0.f};

    for (int kh = 0; kh < 1024; kh += 512) {
        __syncthreads();
        #pragma unroll
        for (int s = 0; s < 8; s++) {       // stage 32x512 bf16 h-tile, coalesced 1KB/wave
            int off = tid * 8 + s * 2048;
            int row = off >> 9;
            int col = off & 511;
            *(uint4*)&hsh[row][col] = *(const uint4*)&h_in[row * 1024 + kh + col];
        }
        __syncthreads();
        #pragma unroll 4
        for (int kk = 0; kk < 512; kk += 32) {
            bf16x8 bfr = *(const bf16x8*)&Whh[jrow * 1024 + kh + kk + lk];  // B direct from L3
            bf16x8 af0 = *(const bf16x8*)&hsh[n     ][kk + lk];
            bf16x8 af1 = *(const bf16x8*)&hsh[16 + n][kk + lk];
            acc0 = __builtin_amdgcn_mfma_f32_16x16x32_bf16(af0, bfr, acc0, 0, 0, 0);
            acc1 = __builtin_amdgcn_mfma_f32_16x16x32_bf16(af1, bfr, acc1, 0, 0, 0);
        }
    }

    // C/D layout: col = lane&15 (= our vc-n), row = (lane>>4)*4 + reg (= batch)
    {
        int brow = (lane >> 4) * 4;
        #pragma unroll
        for (int r = 0; r < 4; r++) {
            gsh[w][brow + r][n]      = acc0[r];
            gsh[w][16 + brow + r][n] = acc1[r];
        }
    }
    __syncthreads();

    #pragma unroll
    for (int p = 0; p < 2; p++) {
        int idx = lane + p * 64;       // 0..127 = 32 b x 4 local-m
        int b   = idx >> 2;
        int ml  = idx & 3;
        int m   = m0 + 4 * w + ml;
        const float4 gv = *(const float4*)&gsh[w][b][ml * 4];  // i,f,g,o
        size_t xbase = ((size_t)b * 256 + t) * 4096 + m;
        float gi = gv.x + bf2f(xproj[xbase]);
        float gf = gv.y + bf2f(xproj[xbase + 1024]);
        float gg = gv.z + bf2f(xproj[xbase + 2048]);
        float go = gv.w + bf2f(xproj[xbase + 3072]);
        float i_ = sigmoidf_fast(gi);
        float f_ = sigmoidf_fast(gf);
        float g_ = tanhf_fast(gg);
        float o_ = sigmoidf_fast(go);
        int cm = b * 1024 + m;
        float c_new = f_ * c_st[cm] + i_ * g_;
        float h_new = o_ * tanhf_fast(c_new);
        c_st[cm]  = c_new;
        h_out[cm] = f2bf(h_new);
        hF[cm]    = h_new;
        size_t so = ((size_t)b * 256 + t) * 1024 + m;
        if (seq_bf)  seq_bf[so]  = f2bf(h_new);
        if (seq_f32) seq_f32[so] = h_new;
    }
}

extern "C" void kernel_launch(void* const* d_in, const int* in_sizes, int n_in,
                              void* d_out, int out_size, void* d_ws, size_t ws_size,
                              hipStream_t stream)
{
    const float* x   = (const float*)d_in[0];
    const float* h0  = (const float*)d_in[1];
    const float* c0  = (const float*)d_in[2];
    const float* Wih = (const float*)d_in[3];
    const float* Whh = (const float*)d_in[4];
    const float* bih = (const float*)d_in[5];
    const float* bhh = (const float*)d_in[6];
    float* out = (float*)d_out;

    // workspace layout (~129 MB total)
    char* p = (char*)d_ws;
    unsigned short* Xproj = (unsigned short*)p; p += (size_t)8192 * 4096 * 2;
    unsigned short* xbf   = (unsigned short*)p; p += (size_t)8192 * 1024 * 2;
    unsigned short* seqbf = (unsigned short*)p; p += (size_t)8192 * 1024 * 2;
    unsigned short* Wihbf = (unsigned short*)p; p += (size_t)2 * 4096 * 1024 * 2;
    unsigned short* Whhbf = (unsigned short*)p; p += (size_t)2 * 4096 * 1024 * 2;
    unsigned short* hbfA  = (unsigned short*)p; p += (size_t)2 * 32 * 1024 * 2;
    unsigned short* hbfB  = (unsigned short*)p; p += (size_t)2 * 32 * 1024 * 2;
    float* hF   = (float*)p; p += (size_t)2 * 32 * 1024 * 4;
    float* cbuf = (float*)p; p += (size_t)2 * 32 * 1024 * 4;

    cvt_f32_to_bf16<<<1024, 256, 0, stream>>>(x,   xbf,   8192 * 1024 / 4);
    cvt_f32_to_bf16<<<1024, 256, 0, stream>>>(Wih, Wihbf, 2 * 4096 * 1024 / 4);
    cvt_f32_to_bf16<<<1024, 256, 0, stream>>>(Whh, Whhbf, 2 * 4096 * 1024 / 4);
    cvt_f32_to_bf16<<<64,   256, 0, stream>>>(h0,  hbfA,  2 * 32 * 1024 / 4);
    hipMemcpyAsync(cbuf, c0, (size_t)2 * 32 * 1024 * 4, hipMemcpyDeviceToDevice, stream);

    for (int l = 0; l < 2; l++) {
        const unsigned short* Ain = (l == 0) ? xbf : seqbf;
        gemm_proj<<<dim3(128, 64), 256, 0, stream>>>(
            Ain, Wihbf + (size_t)l * 4096 * 1024, bih + l * 4096, bhh + l * 4096, Xproj);

        const unsigned short* Whl = Whhbf + (size_t)l * 4096 * 1024;
        unsigned short* hAl = hbfA + l * 32 * 1024;
        unsigned short* hBl = hbfB + l * 32 * 1024;
        float* hFl = hF   + l * 32 * 1024;
        float* cl  = cbuf + l * 32 * 1024;
        unsigned short* sb = (l == 0) ? seqbf : nullptr;
        float* sf          = (l == 1) ? out   : nullptr;
        for (int t = 0; t < 256; t++) {
            const unsigned short* hin = (t & 1) ? hBl : hAl;   // T even -> final fp32 in hF
            unsigned short* hout      = (t & 1) ? hAl : hBl;
            lstm_step<<<64, 256, 0, stream>>>(Whl, Xproj, hin, hout, hFl, cl, sb, sf, t);
        }
    }
    hipMemcpyAsync(out + (size_t)8192 * 1024,         hF,   (size_t)2 * 32 * 1024 * 4,
                   hipMemcpyDeviceToDevice, stream);
    hipMemcpyAsync(out + (size_t)8192 * 1024 + 65536, cbuf, (size_t)2 * 32 * 1024 * 4,
                   hipMemcpyDeviceToDevice, stream);
}